// Round 13
// baseline (81.703 us; speedup 1.0000x reference)
//
#include <hip/hip_runtime.h>

namespace {

constexpr int N    = 8192;
constexpr int M    = 8192;
constexpr int B    = 32;
constexpr int S    = 12;
constexpr int D    = 12;
constexpr int H    = 8;
constexpr int NNZ  = 262144;
constexpr float ALPHA = 0.2f;
constexpr int BD   = B * D;       // 384 floats per row
constexpr int BD2  = BD / 2;      // 192 packed uints per row
constexpr int RU4  = BD / 8;      // 48 uint4 per row
constexpr int CSC_CAP = 128;      // Poisson(32) tail beyond 128: negligible
constexpr int CPB  = 8;           // columns/rows per gather block (8 x 48 lanes)

__device__ __forceinline__ float leaky(float v) { return v >= 0.0f ? v : ALPHA * v; }

// bf16 pair <-> float helpers (bit-exact bf16, RNE)
__device__ __forceinline__ float blo(unsigned v) { return __uint_as_float(v << 16); }
__device__ __forceinline__ float bhi(unsigned v) { return __uint_as_float(v & 0xffff0000u); }
__device__ __forceinline__ unsigned bpack(float a, float b) {
  unsigned x = __float_as_uint(a), y = __float_as_uint(b);
  x = (x + 0x7fffu + ((x >> 16) & 1u)) >> 16;
  y = (y + 0x7fffu + ((y >> 16) & 1u)) & 0xffff0000u;
  return x | y;
}

#define GACC(v)                                        \
  a[0] += blo((v).x); a[1] += bhi((v).x);              \
  a[2] += blo((v).y); a[3] += bhi((v).y);              \
  a[4] += blo((v).z); a[5] += bhi((v).z);              \
  a[6] += blo((v).w); a[7] += bhi((v).w);

#define WACC(v, wt)                                          \
  a[0] += (wt) * blo((v).x); a[1] += (wt) * bhi((v).x);      \
  a[2] += (wt) * blo((v).y); a[3] += (wt) * bhi((v).y);      \
  a[4] += (wt) * blo((v).z); a[5] += (wt) * bhi((v).z);      \
  a[6] += (wt) * blo((v).w); a[7] += (wt) * bhi((v).w);

// K1: xPt[n][b][d] = sum_s x[b][s][n] * P[s][d] (bf16-packed);
//     ax[n][h] for b==0 threads; row_ptr via binary search; zero colfill.
__global__ void k_prep(const float* __restrict__ x, const float* __restrict__ P,
                       const float* __restrict__ W0, const float* __restrict__ A,
                       const int* __restrict__ idx0, unsigned* __restrict__ xPt_u,
                       float* __restrict__ ax, int* __restrict__ row_ptr,
                       int* __restrict__ colfill) {
  __shared__ float w0a_s[H * S];
  int t = blockIdx.x * blockDim.x + threadIdx.x;
  if (blockIdx.x < 32 && threadIdx.x < H * S) {  // w0a[h][s] = sum_d W0[h][s][d]*A[h][d]
    int h = threadIdx.x / S;
    float a = 0.f;
#pragma unroll
    for (int d = 0; d < D; ++d) a += W0[threadIdx.x * D + d] * A[h * 2 * D + d];
    w0a_s[threadIdx.x] = a;
  }
  if (t < M) colfill[t] = 0;
  if (t <= N) {
    int lo = 0, hi = NNZ;
    while (lo < hi) {
      int mid = (lo + hi) >> 1;
      if (idx0[mid] < t) lo = mid + 1; else hi = mid;
    }
    row_ptr[t] = lo;
  }
  if (blockIdx.x < 32) __syncthreads();
  if (t >= B * N) return;
  int b = t >> 13, n = t & (N - 1);
  float xv[S];
#pragma unroll
  for (int s = 0; s < S; ++s) xv[s] = x[((size_t)b * S + s) * N + n];
  float a[D];
#pragma unroll
  for (int d = 0; d < D; ++d) {
    float acc = 0.f;
#pragma unroll
    for (int s = 0; s < S; ++s) acc += xv[s] * P[s * D + d];
    a[d] = acc;
  }
#pragma unroll
  for (int i = 0; i < D / 2; ++i)
    xPt_u[(size_t)n * BD2 + b * (D / 2) + i] = bpack(a[2 * i], a[2 * i + 1]);
  if (b == 0) {  // ax[n][h] = sum_s x0[s]*w0a[h][s]
#pragma unroll
    for (int h = 0; h < H; ++h) {
      float acc = 0.f;
#pragma unroll
      for (int s = 0; s < S; ++s) acc += xv[s] * w0a_s[h * S + s];
      ax[n * H + h] = acc;
    }
  }
}

// K2: fixed-capacity CSC fill; colfill[c] ends as column count.
__global__ void k_fill_csc(const int* __restrict__ idx0, const int* __restrict__ idx1,
                           int* __restrict__ colfill, int* __restrict__ csc_rows) {
  int z = blockIdx.x * blockDim.x + threadIdx.x;
  if (z >= NNZ) return;
  int c = idx1[z];
  int p = atomicAdd(&colfill[c], 1);
  if (p < CSC_CAP) csc_rows[c * CSC_CAP + p] = idx0[z];
}

// K3: 8 columns per block, 48 lanes x uint4 per column (exact R8 structure).
//     e[m] = leaky(sum over edges (r,m) of xPt[r]); bf16-packed out; fused ae.
__global__ void k_e(const uint4* __restrict__ xPt4, const int* __restrict__ colfill,
                    const int* __restrict__ csc_rows, const float* __restrict__ W2,
                    const float* __restrict__ A, uint4* __restrict__ e4,
                    float* __restrict__ ae) {
  int tid = threadIdx.x;               // 0..383
  int col = tid / RU4, lt = tid - col * RU4;
  int m = blockIdx.x * CPB + col;
  __shared__ int rows[CPB][CSC_CAP];
  __shared__ float w2a_s[H * D];
  __shared__ float e0_s[CPB][D];
  int cnt = min(colfill[m], CSC_CAP);
  for (int j = lt; j < cnt; j += RU4) rows[col][j] = csc_rows[m * CSC_CAP + j];
  if (tid < H * D) {  // w2a[h][d] = sum_k W2[h][d][k]*A[h][D+k]
    int h = tid / D;
    float a = 0.f;
#pragma unroll
    for (int k = 0; k < D; ++k) a += W2[tid * D + k] * A[h * 2 * D + D + k];
    w2a_s[tid] = a;
  }
  __syncthreads();
  float a[8] = {0.f, 0.f, 0.f, 0.f, 0.f, 0.f, 0.f, 0.f};
  for (int j = 0; j < cnt; ++j) {
    uint4 v = xPt4[(size_t)rows[col][j] * RU4 + lt];
    GACC(v);
  }
#pragma unroll
  for (int k = 0; k < 8; ++k) a[k] = leaky(a[k]);
  uint4 o;
  o.x = bpack(a[0], a[1]); o.y = bpack(a[2], a[3]);
  o.z = bpack(a[4], a[5]); o.w = bpack(a[6], a[7]);
  e4[(size_t)m * RU4 + lt] = o;
  if (lt == 0) {
#pragma unroll
    for (int k = 0; k < 8; ++k) e0_s[col][k] = a[k];
  } else if (lt == 1) {
#pragma unroll
    for (int k = 0; k < 4; ++k) e0_s[col][8 + k] = a[k];
  }
  __syncthreads();
  if (tid < CPB * H) {
    int c = tid / H, h = tid - c * H;
    float s = 0.f;
#pragma unroll
    for (int d = 0; d < D; ++d) s += e0_s[c][d] * w2a_s[h * D + d];
    ae[(blockIdx.x * CPB + c) * H + h] = s;
  }
}

// K4: fused per-row {stage+logits -> softmax -> weighted gather (R8 serial loop) -> gcn}.
__global__ void k_yw(const int* __restrict__ idx1, const int* __restrict__ row_ptr,
                     const float* __restrict__ ax, const float* __restrict__ ae,
                     const float* __restrict__ lin_w, const float* __restrict__ lin_b,
                     const uint4* __restrict__ e4, const float* __restrict__ gcn_w,
                     const float* __restrict__ gcn_b, float* __restrict__ y) {
  int tid = threadIdx.x;               // 0..383
  int col = tid / RU4, lt = tid - col * RU4;
  int n0 = blockIdx.x * CPB;
  __shared__ float gw_s[D * D];
  __shared__ float gb_s[D];
  __shared__ float ax_s[CPB][H];
  __shared__ float lw_s[H];
  __shared__ float lb_s;
  __shared__ int   beg_s[CPB];
  __shared__ int   cnt_s[CPB];
  __shared__ int   idx_s[CPB][CSC_CAP];
  __shared__ float mt_s[CPB][CSC_CAP];  // logits, then normalized weights
  __shared__ float occ_s[CPB][BD];

  // Phase A1: small loads
  if (tid < D * D) gw_s[tid] = gcn_w[tid];
  if (tid >= 144 && tid < 144 + D) gb_s[tid - 144] = gcn_b[tid - 144];
  if (tid >= 192 && tid < 192 + CPB * H) {
    int u = tid - 192, r = u >> 3, h = u & 7;
    ax_s[r][h] = ax[(n0 + r) * H + h];
  }
  if (tid >= 256 && tid < 256 + H) lw_s[tid - 256] = lin_w[tid - 256];
  if (tid == 256 + H) lb_s = lin_b[0];
  if (tid < CPB) {
    int b = row_ptr[n0 + tid];
    beg_s[tid] = b;
    cnt_s[tid] = min(row_ptr[n0 + tid + 1] - b, CSC_CAP);
  }
  __syncthreads();
  // Phase A2+B: stage edge targets and compute logits in one pass
  {
    int cnt = cnt_s[col], beg = beg_s[col];
    for (int j = lt; j < cnt; j += RU4) {
      int mm = idx1[beg + j];
      idx_s[col][j] = mm;
      float mv = lb_s;
#pragma unroll
      for (int h = 0; h < H; ++h) mv += lw_s[h] * leaky(ax_s[col][h] + ae[mm * H + h]);
      mt_s[col][j] = mv;
    }
  }
  __syncthreads();
  // Phase C: per-wave softmax (wave w handles rows w, w+6)
  {
    int w = tid >> 6, lane = tid & 63;
    for (int r = w; r < CPB; r += 6) {
      int cnt = cnt_s[r];
      if (cnt <= 0) continue;
      float m0 = (lane < cnt) ? mt_s[r][lane] : -3.0e38f;
      float m1 = (lane + 64 < cnt) ? mt_s[r][lane + 64] : -3.0e38f;
      float mx = fmaxf(m0, m1);
#pragma unroll
      for (int off = 32; off; off >>= 1) mx = fmaxf(mx, __shfl_xor(mx, off));
      float p0 = (lane < cnt) ? expf(m0 - mx) : 0.f;
      float p1 = (lane + 64 < cnt) ? expf(m1 - mx) : 0.f;
      float sum = p0 + p1;
#pragma unroll
      for (int off = 32; off; off >>= 1) sum += __shfl_xor(sum, off);
      float inv = 1.0f / sum;
      if (lane < cnt) mt_s[r][lane] = p0 * inv;
      if (lane + 64 < cnt) mt_s[r][lane + 64] = p1 * inv;
    }
  }
  __syncthreads();
  // Phase D: weighted gather (R8 serial loop, low VGPR)
  float a[8] = {0.f, 0.f, 0.f, 0.f, 0.f, 0.f, 0.f, 0.f};
  int cnt = cnt_s[col];
  if (cnt > 0) {
    for (int j = 0; j < cnt; ++j) {
      uint4 v = e4[(size_t)idx_s[col][j] * RU4 + lt];
      float wt = mt_s[col][j];
      WACC(v, wt);
    }
  } else {
    // empty row: uniform softmax over all M columns (never taken for this input)
    for (int mm = 0; mm < M; ++mm) {
      uint4 v = e4[(size_t)mm * RU4 + lt];
      GACC(v);
    }
#pragma unroll
    for (int k = 0; k < 8; ++k) a[k] *= (1.0f / (float)M);
  }
#pragma unroll
  for (int k = 0; k < 8; ++k) occ_s[col][8 * lt + k] = a[k];
  __syncthreads();
  // Phase E: gcn epilogue, coalesced: 96-lane group writes 384B contiguous per b
  {
    int q = tid / 96, r = tid - q * 96;
    int c = r / D, d = r - c * D;
#pragma unroll
    for (int bi = 0; bi < 8; ++bi) {
      int b = bi * 4 + q;
      float s = gb_s[d];
#pragma unroll
      for (int k = 0; k < D; ++k) s += occ_s[c][b * D + k] * gw_s[d * D + k];
      y[(size_t)b * N * D + (size_t)(n0 + c) * D + d] = leaky(s);
    }
  }
}

}  // namespace

extern "C" void kernel_launch(void* const* d_in, const int* in_sizes, int n_in,
                              void* d_out, int out_size, void* d_ws, size_t ws_size,
                              hipStream_t stream) {
  const float* x     = (const float*)d_in[0];
  // d_in[1] = hg (dense 256 MB) -- intentionally unused
  const int*   idx0  = (const int*)d_in[2];
  const int*   idx1  = (const int*)d_in[3];
  const float* P     = (const float*)d_in[4];
  const float* W0    = (const float*)d_in[5];
  const float* A     = (const float*)d_in[6];
  const float* W2    = (const float*)d_in[7];
  const float* lin_w = (const float*)d_in[8];
  const float* lin_b = (const float*)d_in[9];
  const float* gcn_w = (const float*)d_in[10];
  const float* gcn_b = (const float*)d_in[11];
  float* y = (float*)d_out;

  char* ws = (char*)d_ws;
  size_t off = 0;
  auto carve = [&](size_t bytes) {
    char* p = ws + off;
    off = (off + bytes + 255) & ~(size_t)255;
    return p;
  };
  unsigned* xPt_u   = (unsigned*)carve(sizeof(unsigned) * (size_t)N * BD2);
  unsigned* e_u     = (unsigned*)carve(sizeof(unsigned) * (size_t)M * BD2);
  float*    ax      = (float*)carve(sizeof(float) * N * H);
  float*    ae      = (float*)carve(sizeof(float) * M * H);
  int*      colfill = (int*)carve(sizeof(int) * M);
  int*      row_ptr = (int*)carve(sizeof(int) * (N + 1));
  int*      csc_rows= (int*)carve(sizeof(int) * (size_t)M * CSC_CAP);
  (void)ws_size; (void)in_sizes; (void)n_in; (void)out_size;

  k_prep<<<(B * N + 255) / 256, 256, 0, stream>>>(x, P, W0, A, idx0, xPt_u, ax,
                                                  row_ptr, colfill);
  k_fill_csc<<<(NNZ + 255) / 256, 256, 0, stream>>>(idx0, idx1, colfill, csc_rows);
  k_e<<<M / CPB, 384, 0, stream>>>((const uint4*)xPt_u, colfill, csc_rows, W2, A,
                                   (uint4*)e_u, ae);
  k_yw<<<N / CPB, 384, 0, stream>>>(idx1, row_ptr, ax, ae, lin_w, lin_b,
                                    (const uint4*)e_u, gcn_w, gcn_b, y);
}

// Round 14
// 67.444 us; speedup vs baseline: 1.2114x; 1.2114x over previous
//
#include <hip/hip_runtime.h>

namespace {

constexpr int N    = 8192;
constexpr int M    = 8192;
constexpr int B    = 32;
constexpr int S    = 12;
constexpr int D    = 12;
constexpr int H    = 8;
constexpr int NNZ  = 262144;
constexpr float ALPHA = 0.2f;
constexpr int BD   = B * D;       // 384 floats per row
constexpr int BD2  = BD / 2;      // 192 packed uints per row
constexpr int RU4  = BD / 8;      // 48 uint4 per row
constexpr int CSC_CAP = 128;      // Poisson(32) tail beyond 128: negligible
constexpr int CPB  = 8;           // columns/rows per gather block (8 x 48 lanes)

__device__ __forceinline__ float leaky(float v) { return v >= 0.0f ? v : ALPHA * v; }

// bf16 pair <-> float helpers (bit-exact bf16, RNE)
__device__ __forceinline__ float blo(unsigned v) { return __uint_as_float(v << 16); }
__device__ __forceinline__ float bhi(unsigned v) { return __uint_as_float(v & 0xffff0000u); }
__device__ __forceinline__ unsigned bpack(float a, float b) {
  unsigned x = __float_as_uint(a), y = __float_as_uint(b);
  x = (x + 0x7fffu + ((x >> 16) & 1u)) >> 16;
  y = (y + 0x7fffu + ((y >> 16) & 1u)) & 0xffff0000u;
  return x | y;
}

// K1: xPt[n][b][d] = sum_s x[b][s][n] * P[s][d] (bf16-packed);
//     ax[n][h] for b==0 threads; row_ptr via binary search; zero colfill.
__global__ void k_prep(const float* __restrict__ x, const float* __restrict__ P,
                       const float* __restrict__ W0, const float* __restrict__ A,
                       const int* __restrict__ idx0, unsigned* __restrict__ xPt_u,
                       float* __restrict__ ax, int* __restrict__ row_ptr,
                       int* __restrict__ colfill) {
  __shared__ float w0a_s[H * S];
  int t = blockIdx.x * blockDim.x + threadIdx.x;
  if (blockIdx.x < 32 && threadIdx.x < H * S) {  // w0a[h][s] = sum_d W0[h][s][d]*A[h][d]
    int h = threadIdx.x / S;
    float a = 0.f;
#pragma unroll
    for (int d = 0; d < D; ++d) a += W0[threadIdx.x * D + d] * A[h * 2 * D + d];
    w0a_s[threadIdx.x] = a;
  }
  if (t < M) colfill[t] = 0;
  if (t <= N) {
    int lo = 0, hi = NNZ;
    while (lo < hi) {
      int mid = (lo + hi) >> 1;
      if (idx0[mid] < t) lo = mid + 1; else hi = mid;
    }
    row_ptr[t] = lo;
  }
  if (blockIdx.x < 32) __syncthreads();
  if (t >= B * N) return;
  int b = t >> 13, n = t & (N - 1);
  float xv[S];
#pragma unroll
  for (int s = 0; s < S; ++s) xv[s] = x[((size_t)b * S + s) * N + n];
  float a[D];
#pragma unroll
  for (int d = 0; d < D; ++d) {
    float acc = 0.f;
#pragma unroll
    for (int s = 0; s < S; ++s) acc += xv[s] * P[s * D + d];
    a[d] = acc;
  }
#pragma unroll
  for (int i = 0; i < D / 2; ++i)
    xPt_u[(size_t)n * BD2 + b * (D / 2) + i] = bpack(a[2 * i], a[2 * i + 1]);
  if (b == 0) {  // ax[n][h] = sum_s x0[s]*w0a[h][s]
#pragma unroll
    for (int h = 0; h < H; ++h) {
      float acc = 0.f;
#pragma unroll
      for (int s = 0; s < S; ++s) acc += xv[s] * w0a_s[h * S + s];
      ax[n * H + h] = acc;
    }
  }
}

// K2: fixed-capacity CSC fill; colfill[c] ends as column count.
__global__ void k_fill_csc(const int* __restrict__ idx0, const int* __restrict__ idx1,
                           int* __restrict__ colfill, int* __restrict__ csc_rows) {
  int z = blockIdx.x * blockDim.x + threadIdx.x;
  if (z >= NNZ) return;
  int c = idx1[z];
  int p = atomicAdd(&colfill[c], 1);
  if (p < CSC_CAP) csc_rows[c * CSC_CAP + p] = idx0[z];
}

// K3: 8 columns per block, 48 lanes x uint4 per column.
//     e[m] = leaky(sum over edges (r,m) of xPt[r]); bf16-packed out; fused ae.
__global__ void k_e(const uint4* __restrict__ xPt4, const int* __restrict__ colfill,
                    const int* __restrict__ csc_rows, const float* __restrict__ W2,
                    const float* __restrict__ A, uint4* __restrict__ e4,
                    float* __restrict__ ae) {
  int tid = threadIdx.x;               // 0..383
  int col = tid / RU4, lt = tid - col * RU4;
  int m = blockIdx.x * CPB + col;
  __shared__ int rows[CPB][CSC_CAP];
  __shared__ float w2a_s[H * D];
  __shared__ float e0_s[CPB][D];
  int cnt = min(colfill[m], CSC_CAP);
  for (int j = lt; j < cnt; j += RU4) rows[col][j] = csc_rows[m * CSC_CAP + j];
  if (tid < H * D) {  // w2a[h][d] = sum_k W2[h][d][k]*A[h][D+k]
    int h = tid / D;
    float a = 0.f;
#pragma unroll
    for (int k = 0; k < D; ++k) a += W2[tid * D + k] * A[h * 2 * D + D + k];
    w2a_s[tid] = a;
  }
  __syncthreads();
  float a[8] = {0.f, 0.f, 0.f, 0.f, 0.f, 0.f, 0.f, 0.f};
  for (int j = 0; j < cnt; ++j) {
    uint4 v = xPt4[(size_t)rows[col][j] * RU4 + lt];
    a[0] += blo(v.x); a[1] += bhi(v.x);
    a[2] += blo(v.y); a[3] += bhi(v.y);
    a[4] += blo(v.z); a[5] += bhi(v.z);
    a[6] += blo(v.w); a[7] += bhi(v.w);
  }
#pragma unroll
  for (int k = 0; k < 8; ++k) a[k] = leaky(a[k]);
  uint4 o;
  o.x = bpack(a[0], a[1]); o.y = bpack(a[2], a[3]);
  o.z = bpack(a[4], a[5]); o.w = bpack(a[6], a[7]);
  e4[(size_t)m * RU4 + lt] = o;
  if (lt == 0) {
#pragma unroll
    for (int k = 0; k < 8; ++k) e0_s[col][k] = a[k];
  } else if (lt == 1) {
#pragma unroll
    for (int k = 0; k < 4; ++k) e0_s[col][8 + k] = a[k];
  }
  __syncthreads();
  if (tid < CPB * H) {
    int c = tid / H, h = tid - c * H;
    float s = 0.f;
#pragma unroll
    for (int d = 0; d < D; ++d) s += e0_s[c][d] * w2a_s[h * D + d];
    ae[(blockIdx.x * CPB + c) * H + h] = s;
  }
}

// K4: fused per-row {logits -> softmax -> weighted gather -> gcn}. 8 rows/block.
__global__ void k_yw(const int* __restrict__ idx1, const int* __restrict__ row_ptr,
                     const float* __restrict__ ax, const float* __restrict__ ae,
                     const float* __restrict__ lin_w, const float* __restrict__ lin_b,
                     const uint4* __restrict__ e4, const float* __restrict__ gcn_w,
                     const float* __restrict__ gcn_b, float* __restrict__ y) {
  int tid = threadIdx.x;               // 0..383
  int col = tid / RU4, lt = tid - col * RU4;
  int n0 = blockIdx.x * CPB;
  __shared__ float gw_s[D * D];
  __shared__ float gb_s[D];
  __shared__ float ax_s[CPB][H];
  __shared__ float lw_s[H];
  __shared__ float lb_s;
  __shared__ int   beg_s[CPB];
  __shared__ int   cnt_s[CPB];
  __shared__ int   idx_s[CPB][CSC_CAP];
  __shared__ float mt_s[CPB][CSC_CAP];  // logits, then normalized weights
  __shared__ float occ_s[CPB][BD];

  // Phase A1: small loads
  if (tid < D * D) gw_s[tid] = gcn_w[tid];
  if (tid >= 144 && tid < 144 + D) gb_s[tid - 144] = gcn_b[tid - 144];
  if (tid >= 192 && tid < 192 + CPB * H) {
    int u = tid - 192, r = u >> 3, h = u & 7;
    ax_s[r][h] = ax[(n0 + r) * H + h];
  }
  if (tid >= 256 && tid < 256 + H) lw_s[tid - 256] = lin_w[tid - 256];
  if (tid == 256 + H) lb_s = lin_b[0];
  if (tid < CPB) {
    int b = row_ptr[n0 + tid];
    beg_s[tid] = b;
    cnt_s[tid] = min(row_ptr[n0 + tid + 1] - b, CSC_CAP);
  }
  __syncthreads();
  // Phase A2: stage edge targets
  for (int j = lt; j < cnt_s[col]; j += RU4) idx_s[col][j] = idx1[beg_s[col] + j];
  __syncthreads();
  // Phase B: logits for all edges of all 8 rows (flat distribution)
  for (int j0 = tid; j0 < CPB * CSC_CAP; j0 += 384) {
    int r = j0 >> 7, jj = j0 & (CSC_CAP - 1);
    if (jj < cnt_s[r]) {
      int mm = idx_s[r][jj];
      float mv = lb_s;
#pragma unroll
      for (int h = 0; h < H; ++h) mv += lw_s[h] * leaky(ax_s[r][h] + ae[mm * H + h]);
      mt_s[r][jj] = mv;
    }
  }
  __syncthreads();
  // Phase C: per-wave softmax (wave w handles rows w, w+6)
  {
    int w = tid >> 6, lane = tid & 63;
    for (int r = w; r < CPB; r += 6) {
      int cnt = cnt_s[r];
      if (cnt <= 0) continue;
      float m0 = (lane < cnt) ? mt_s[r][lane] : -3.0e38f;
      float m1 = (lane + 64 < cnt) ? mt_s[r][lane + 64] : -3.0e38f;
      float mx = fmaxf(m0, m1);
#pragma unroll
      for (int off = 32; off; off >>= 1) mx = fmaxf(mx, __shfl_xor(mx, off));
      float p0 = (lane < cnt) ? expf(m0 - mx) : 0.f;
      float p1 = (lane + 64 < cnt) ? expf(m1 - mx) : 0.f;
      float sum = p0 + p1;
#pragma unroll
      for (int off = 32; off; off >>= 1) sum += __shfl_xor(sum, off);
      float inv = 1.0f / sum;
      if (lane < cnt) mt_s[r][lane] = p0 * inv;
      if (lane + 64 < cnt) mt_s[r][lane + 64] = p1 * inv;
    }
  }
  __syncthreads();
  // Phase D: weighted gather
  float a[8] = {0.f, 0.f, 0.f, 0.f, 0.f, 0.f, 0.f, 0.f};
  int cnt = cnt_s[col];
  if (cnt > 0) {
    for (int j = 0; j < cnt; ++j) {
      uint4 v = e4[(size_t)idx_s[col][j] * RU4 + lt];
      float w = mt_s[col][j];
      a[0] += w * blo(v.x); a[1] += w * bhi(v.x);
      a[2] += w * blo(v.y); a[3] += w * bhi(v.y);
      a[4] += w * blo(v.z); a[5] += w * bhi(v.z);
      a[6] += w * blo(v.w); a[7] += w * bhi(v.w);
    }
  } else {
    // empty row: uniform softmax over all M columns (never taken for this input)
    for (int mm = 0; mm < M; ++mm) {
      uint4 v = e4[(size_t)mm * RU4 + lt];
      a[0] += blo(v.x); a[1] += bhi(v.x);
      a[2] += blo(v.y); a[3] += bhi(v.y);
      a[4] += blo(v.z); a[5] += bhi(v.z);
      a[6] += blo(v.w); a[7] += bhi(v.w);
    }
#pragma unroll
    for (int k = 0; k < 8; ++k) a[k] *= (1.0f / (float)M);
  }
#pragma unroll
  for (int k = 0; k < 8; ++k) occ_s[col][8 * lt + k] = a[k];
  __syncthreads();
  // Phase E: gcn epilogue
  int b = tid / D, d = tid - b * D;
#pragma unroll
  for (int c = 0; c < CPB; ++c) {
    float s = gb_s[d];
#pragma unroll
    for (int k = 0; k < D; ++k) s += occ_s[c][b * D + k] * gw_s[d * D + k];
    y[(size_t)b * N * D + (size_t)(n0 + c) * D + d] = leaky(s);
  }
}

}  // namespace

extern "C" void kernel_launch(void* const* d_in, const int* in_sizes, int n_in,
                              void* d_out, int out_size, void* d_ws, size_t ws_size,
                              hipStream_t stream) {
  const float* x     = (const float*)d_in[0];
  // d_in[1] = hg (dense 256 MB) -- intentionally unused
  const int*   idx0  = (const int*)d_in[2];
  const int*   idx1  = (const int*)d_in[3];
  const float* P     = (const float*)d_in[4];
  const float* W0    = (const float*)d_in[5];
  const float* A     = (const float*)d_in[6];
  const float* W2    = (const float*)d_in[7];
  const float* lin_w = (const float*)d_in[8];
  const float* lin_b = (const float*)d_in[9];
  const float* gcn_w = (const float*)d_in[10];
  const float* gcn_b = (const float*)d_in[11];
  float* y = (float*)d_out;

  char* ws = (char*)d_ws;
  size_t off = 0;
  auto carve = [&](size_t bytes) {
    char* p = ws + off;
    off = (off + bytes + 255) & ~(size_t)255;
    return p;
  };
  unsigned* xPt_u   = (unsigned*)carve(sizeof(unsigned) * (size_t)N * BD2);
  unsigned* e_u     = (unsigned*)carve(sizeof(unsigned) * (size_t)M * BD2);
  float*    ax      = (float*)carve(sizeof(float) * N * H);
  float*    ae      = (float*)carve(sizeof(float) * M * H);
  int*      colfill = (int*)carve(sizeof(int) * M);
  int*      row_ptr = (int*)carve(sizeof(int) * (N + 1));
  int*      csc_rows= (int*)carve(sizeof(int) * (size_t)M * CSC_CAP);
  (void)ws_size; (void)in_sizes; (void)n_in; (void)out_size;

  k_prep<<<(B * N + 255) / 256, 256, 0, stream>>>(x, P, W0, A, idx0, xPt_u, ax,
                                                  row_ptr, colfill);
  k_fill_csc<<<(NNZ + 255) / 256, 256, 0, stream>>>(idx0, idx1, colfill, csc_rows);
  k_e<<<M / CPB, 384, 0, stream>>>((const uint4*)xPt_u, colfill, csc_rows, W2, A,
                                   (uint4*)e_u, ae);
  k_yw<<<N / CPB, 384, 0, stream>>>(idx1, row_ptr, ax, ae, lin_w, lin_b,
                                    (const uint4*)e_u, gcn_w, gcn_b, y);
}